// Round 7
// baseline (549.030 us; speedup 1.0000x reference)
//
#include <hip/hip_runtime.h>
#include <math.h>

#define NB 8
#define NC 128
#define NP 96
#define ND 128
#define NH 8
#define NR 16

typedef __attribute__((ext_vector_type(8))) short short8;
typedef __attribute__((ext_vector_type(4))) float f32x4;
typedef __attribute__((ext_vector_type(4))) unsigned u32x4;

#define MFMA(a, b, c) __builtin_amdgcn_mfma_f32_16x16x32_bf16((a), (b), (c), 0, 0, 0)

__device__ __forceinline__ short8 s8(u32x4 u) { return __builtin_bit_cast(short8, u); }

// scalar fp32 -> bf16 (RNE) and back
__device__ __forceinline__ unsigned bfh_u(float x) {
  unsigned u = __float_as_uint(x);
  unsigned r = u + 0x7fffu + ((u >> 16) & 1u);
  return r >> 16;  // bf16 bits in low 16
}
__device__ __forceinline__ short bfh(float x) { return (short)bfh_u(x); }
__device__ __forceinline__ float bff(short s) {
  return __uint_as_float(((unsigned)(unsigned short)s) << 16);
}

// pair split: {hi_packed, lo_packed}, elem a in low 16 bits of each word
__device__ __forceinline__ uint2 split2(float a, float b) {
  unsigned ha = bfh_u(a), hb = bfh_u(b);
  float fa = __uint_as_float(ha << 16), fb = __uint_as_float(hb << 16);
  unsigned la = bfh_u(a - fa), lb = bfh_u(b - fb);
  return make_uint2(ha | (hb << 16), la | (lb << 16));
}

// split 8 consecutive floats into hi/lo packed u32x4
__device__ __forceinline__ void split8(const float4 x0, const float4 x1,
                                       u32x4* hi, u32x4* lo) {
  uint2 r0 = split2(x0.x, x0.y), r1 = split2(x0.z, x0.w);
  uint2 r2 = split2(x1.x, x1.y), r3 = split2(x1.z, x1.w);
  *hi = u32x4{r0.x, r1.x, r2.x, r3.x};
  *lo = u32x4{r0.y, r1.y, r2.y, r3.y};
}

// LDS row strides in shorts
#define TS_Z 136   // z      [rows][136]
#define TS_Q 72    // Q2     [rows][72]
#define TS_T 104   // zT/abar[rows][104]

#define W_ELEMS ((size_t)4 * 8 * 128 * 128)  // 524288 per split
#define W_NEED (W_ELEMS * 2 * 2)             // 2 MB

// ---------------- W split precompute: mats {tu, tv, cu, cv} ----------------
__global__ __launch_bounds__(256)
void prep_w(const float* __restrict__ w0, const float* __restrict__ w1,
            const float* __restrict__ w2, const float* __restrict__ w3,
            short* __restrict__ whi, short* __restrict__ wlo) {
  int t = blockIdx.x * 256 + threadIdx.x;   // 65536 threads, 8 elems each
  int mat = t >> 14;
  size_t off = (size_t)(t & 16383) * 8;
  const float* srcs[4] = {w0, w1, w2, w3};
  const float* s = srcs[mat] + off;
  u32x4 hi, lo;
  split8(*(const float4*)s, *(const float4*)(s + 4), &hi, &lo);
  size_t base = (size_t)mat * 131072 + off;
  *(u32x4*)&whi[base] = hi;
  *(u32x4*)&wlo[base] = lo;
}

// ---------------- time-message kernel: one block per (b,c) ----------------
template <int WS>
__global__ __launch_bounds__(512, 4)
void tmsg_kernel(const float* __restrict__ qz, const float* __restrict__ wu,
                 const float* __restrict__ wv, const short* __restrict__ whi,
                 const short* __restrict__ wlo, float* __restrict__ out) {
  __shared__ __align__(16) short smem[39936];
  short* zhi = smem;                   // [96][136]
  short* zlo = smem + NP * TS_Z;
  short* qhi = smem + 2 * NP * TS_Z;   // [96][72]
  short* qlo = qhi + NP * TS_Q;
  short* zthi = smem;                  // [128][104] (phase2, aliased)
  short* ztlo = smem + ND * TS_T;
  short* ahi  = smem + 2 * ND * TS_T;  // [96][104]  (phase2)

  const int tid = threadIdx.x;
  const int l = tid & 63, w = tid >> 6;
  const int lm = l & 15, lk = l >> 4;
  const int c = blockIdx.x, b = blockIdx.y;
  const float* zg = qz + ((size_t)(b * NC + c) * NP) * ND;

  const int nt = w & 3, mset = (w >> 2) * 3;  // wave owns fixed nt, 3 m-tiles
  const int vsel = nt & 1, hsel = nt >> 1;
  const float qsc = vsel ? 1.0f : 0.25f;  // fold 1/sqrt(R) into Qu

  // ---- hoist ALL W fragments (4 head-pairs) to kernel entry ----
  u32x4 wbh[4][4], wbl[4][4];
#pragma unroll
  for (int hp = 0; hp < 4; ++hp) {
    const int hd = 2 * hp + hsel;
    if constexpr (WS) {
      const size_t rb = (((size_t)vsel * 8 + b) * 128 + hd * NR + lm) * 128;
#pragma unroll
      for (int ks = 0; ks < 4; ++ks) {
        wbh[hp][ks] = *(const u32x4*)&whi[rb + ks * 32 + lk * 8];
        wbl[hp][ks] = *(const u32x4*)&wlo[rb + ks * 32 + lk * 8];
      }
    } else {
      const float* wrow = (vsel ? wv : wu) + ((size_t)b * ND + hd * NR + lm) * ND;
#pragma unroll
      for (int ks = 0; ks < 4; ++ks)
        split8(*(const float4*)(wrow + ks * 32 + lk * 8),
               *(const float4*)(wrow + ks * 32 + lk * 8 + 4),
               &wbh[hp][ks], &wbl[hp][ks]);
    }
  }

  // ---- stage z -> split bf16 ----
  for (int i = tid; i < NP * 32; i += 512) {
    int p = i >> 5, s = i & 31;
    float4 v = ((const float4*)zg)[i];
    uint2 r0 = split2(v.x, v.y), r1 = split2(v.z, v.w);
    *(uint2*)&zhi[p * TS_Z + 4 * s] = make_uint2(r0.x, r1.x);
    *(uint2*)&zlo[p * TS_Z + 4 * s] = make_uint2(r0.y, r1.y);
  }
  __syncthreads();

  float aacc[4][6] = {};
  const short8 z8 = {0, 0, 0, 0, 0, 0, 0, 0};
  const f32x4 zf = {0.f, 0.f, 0.f, 0.f};

  for (int hp = 0; hp < 4; ++hp) {
    // ---- projection: Q tiles (m, nt) for m in mset..mset+2 ----
    f32x4 pacc[3] = {zf, zf, zf};
#pragma unroll
    for (int ks = 0; ks < 4; ++ks) {
#pragma unroll
      for (int mm = 0; mm < 3; ++mm) {
        int row = (mset + mm) * 16 + lm;
        short8 ah = *(const short8*)&zhi[row * TS_Z + ks * 32 + lk * 8];
        short8 al = *(const short8*)&zlo[row * TS_Z + ks * 32 + lk * 8];
        pacc[mm] = MFMA(ah, s8(wbh[hp][ks]), pacc[mm]);
        pacc[mm] = MFMA(ah, s8(wbl[hp][ks]), pacc[mm]);
        pacc[mm] = MFMA(al, s8(wbh[hp][ks]), pacc[mm]);
      }
    }
#pragma unroll
    for (int mm = 0; mm < 3; ++mm) {
#pragma unroll
      for (int r = 0; r < 4; ++r) {
        float v = pacc[mm][r] * qsc;
        int row = (mset + mm) * 16 + lk * 4 + r, col = nt * 16 + lm;
        short hh = bfh(v);
        qhi[row * TS_Q + col] = hh;
        qlo[row * TS_Q + col] = bfh(v - bff(hh));
      }
    }
    __syncthreads();

    // ---- logits (K=16 zero-padded) + softmax (no max-sub); waves 0-5 ----
    if (w < 6) {
#pragma unroll
      for (int hh = 0; hh < 2; ++hh) {
        short8 ah = z8, al = z8;
        if (l < 32) {
          ah = *(const short8*)&qhi[(w * 16 + lm) * TS_Q + 32 * hh + lk * 8];
          al = *(const short8*)&qlo[(w * 16 + lm) * TS_Q + 32 * hh + lk * 8];
        }
        f32x4 s[6];
#pragma unroll
        for (int qt = 0; qt < 6; ++qt) {
          s[qt] = zf;
          short8 bh = z8, bl = z8;
          if (l < 32) {
            bh = *(const short8*)&qhi[(qt * 16 + lm) * TS_Q + 32 * hh + 16 + lk * 8];
            bl = *(const short8*)&qlo[(qt * 16 + lm) * TS_Q + 32 * hh + 16 + lk * 8];
          }
          s[qt] = MFMA(ah, bh, s[qt]);
          s[qt] = MFMA(ah, bl, s[qt]);
          s[qt] = MFMA(al, bh, s[qt]);
        }
#pragma unroll
        for (int r = 0; r < 4; ++r) {
          float e[6], sum = 0.f;
#pragma unroll
          for (int qt = 0; qt < 6; ++qt) { e[qt] = __expf(s[qt][r]); sum += e[qt]; }
          sum += __shfl_xor(sum, 1);
          sum += __shfl_xor(sum, 2);
          sum += __shfl_xor(sum, 4);
          sum += __shfl_xor(sum, 8);
          float inv = 1.0f / sum;
#pragma unroll
          for (int qt = 0; qt < 6; ++qt) aacc[r][qt] += e[qt] * inv;
        }
      }
    }
    __syncthreads();
  }

  // ---- phase2: build zT split + abar-hi in aliased LDS ----
  for (int i = tid; i < NP * 32; i += 512) {
    int p = i >> 5, s = i & 31;
    float4 v = ((const float4*)zg)[i];
    float f[4] = {v.x, v.y, v.z, v.w};
#pragma unroll
    for (int j = 0; j < 4; ++j) {
      int d = 4 * s + j;
      short hh = bfh(f[j]);
      zthi[d * TS_T + p] = hh;
      ztlo[d * TS_T + p] = bfh(f[j] - bff(hh));
    }
  }
  if (w < 6) {
#pragma unroll
    for (int r = 0; r < 4; ++r)
#pragma unroll
      for (int qt = 0; qt < 6; ++qt)
        ahi[(w * 16 + lk * 4 + r) * TS_T + qt * 16 + lm] = bfh(aacc[r][qt] * 0.125f);
  }
  __syncthreads();

  // ---- PV: m_t = abar @ z ; wave w owns d-tile w; K=96 ----
  float* og = out + ((size_t)(b * NC + c) * NP) * ND;
  f32x4 oacc[6] = {zf, zf, zf, zf, zf, zf};
#pragma unroll
  for (int ks = 0; ks < 3; ++ks) {
    short8 bh = *(const short8*)&zthi[(w * 16 + lm) * TS_T + ks * 32 + lk * 8];
    short8 bl = *(const short8*)&ztlo[(w * 16 + lm) * TS_T + ks * 32 + lk * 8];
#pragma unroll
    for (int m = 0; m < 6; ++m) {
      short8 a = *(const short8*)&ahi[(m * 16 + lm) * TS_T + ks * 32 + lk * 8];
      oacc[m] = MFMA(a, bh, oacc[m]);
      oacc[m] = MFMA(a, bl, oacc[m]);
    }
  }
#pragma unroll
  for (int m = 0; m < 6; ++m)
#pragma unroll
    for (int r = 0; r < 4; ++r)
      og[(m * 16 + lk * 4 + r) * ND + w * 16 + lm] = oacc[m][r];
}

// ---------------- channel-message kernel: one block per (b,p) ----------------
// NEW: wave w owns m-tile w (16 c-rows); z A-fragments live in REGISTERS
// (loaded once from global, split once). LDS holds only Q (36,864 B) ->
// 4 blocks/CU occupancy target. abar stays in registers; epilogue reads
// exact fp32 z from global (L2/L3-hot).
template <int WS>
__global__ __launch_bounds__(512, 8)
void cmsg_kernel(const float* __restrict__ qz, const float* __restrict__ wu,
                 const float* __restrict__ wv, const short* __restrict__ whi,
                 const short* __restrict__ wlo, float* __restrict__ out) {
  __shared__ __align__(16) short qhi_s[NC * TS_Q];  // [128][72]
  __shared__ __align__(16) short qlo_s[NC * TS_Q];

  const int tid = threadIdx.x;
  const int l = tid & 63, w = tid >> 6;
  const int lm = l & 15, lk = l >> 4;
  const int p = blockIdx.x, b = blockIdx.y;

  // ---- z A-fragments for this wave's m-tile (rows w*16+lm), split in regs ----
  u32x4 zah[4], zal[4];
  {
    const float* zrow = qz + ((size_t)(b * NC + w * 16 + lm) * NP + p) * ND;
#pragma unroll
    for (int ks = 0; ks < 4; ++ks)
      split8(*(const float4*)(zrow + ks * 32 + lk * 8),
             *(const float4*)(zrow + ks * 32 + lk * 8 + 4), &zah[ks], &zal[ks]);
  }

  float aacc[4][8] = {};
  const short8 z8 = {0, 0, 0, 0, 0, 0, 0, 0};
  const f32x4 zf = {0.f, 0.f, 0.f, 0.f};

  for (int hp = 0; hp < 4; ++hp) {
    // ---- projection: wave w computes Q[m-tile w][all 4 nt] ----
#pragma unroll
    for (int nt = 0; nt < 4; ++nt) {
      const int vsel = nt & 1, hd = 2 * hp + (nt >> 1);
      u32x4 wbh[4], wbl[4];
      if constexpr (WS) {
        const size_t rb = (((size_t)(2 + vsel) * 8 + b) * 128 + hd * NR + lm) * 128;
#pragma unroll
        for (int ks = 0; ks < 4; ++ks) {
          wbh[ks] = *(const u32x4*)&whi[rb + ks * 32 + lk * 8];
          wbl[ks] = *(const u32x4*)&wlo[rb + ks * 32 + lk * 8];
        }
      } else {
        const float* wrow = (vsel ? wv : wu) + ((size_t)b * ND + hd * NR + lm) * ND;
#pragma unroll
        for (int ks = 0; ks < 4; ++ks)
          split8(*(const float4*)(wrow + ks * 32 + lk * 8),
                 *(const float4*)(wrow + ks * 32 + lk * 8 + 4), &wbh[ks], &wbl[ks]);
      }
      f32x4 pacc = zf;
#pragma unroll
      for (int ks = 0; ks < 4; ++ks) {
        pacc = MFMA(s8(zah[ks]), s8(wbh[ks]), pacc);
        pacc = MFMA(s8(zah[ks]), s8(wbl[ks]), pacc);
        pacc = MFMA(s8(zal[ks]), s8(wbh[ks]), pacc);
      }
      const float qsc = vsel ? 1.0f : 0.25f;
#pragma unroll
      for (int r = 0; r < 4; ++r) {
        float v = pacc[r] * qsc;
        int row = w * 16 + lk * 4 + r, col = nt * 16 + lm;
        short hh = bfh(v);
        qhi_s[row * TS_Q + col] = hh;
        qlo_s[row * TS_Q + col] = bfh(v - bff(hh));
      }
    }
    __syncthreads();

    // ---- logits (K=16 padded) + softmax over d' (no max-sub) ----
#pragma unroll
    for (int hh = 0; hh < 2; ++hh) {
      short8 ah = z8, al = z8;
      if (l < 32) {
        ah = *(const short8*)&qhi_s[(w * 16 + lm) * TS_Q + 32 * hh + lk * 8];
        al = *(const short8*)&qlo_s[(w * 16 + lm) * TS_Q + 32 * hh + lk * 8];
      }
      f32x4 s[8];
#pragma unroll
      for (int qt = 0; qt < 8; ++qt) {
        s[qt] = zf;
        short8 bh = z8, bl = z8;
        if (l < 32) {
          bh = *(const short8*)&qhi_s[(qt * 16 + lm) * TS_Q + 32 * hh + 16 + lk * 8];
          bl = *(const short8*)&qlo_s[(qt * 16 + lm) * TS_Q + 32 * hh + 16 + lk * 8];
        }
        s[qt] = MFMA(ah, bh, s[qt]);
        s[qt] = MFMA(ah, bl, s[qt]);
        s[qt] = MFMA(al, bh, s[qt]);
      }
#pragma unroll
      for (int r = 0; r < 4; ++r) {
        float e[8], sum = 0.f;
#pragma unroll
        for (int qt = 0; qt < 8; ++qt) { e[qt] = __expf(s[qt][r]); sum += e[qt]; }
        sum += __shfl_xor(sum, 1);
        sum += __shfl_xor(sum, 2);
        sum += __shfl_xor(sum, 4);
        sum += __shfl_xor(sum, 8);
        float inv = 1.0f / sum;
#pragma unroll
        for (int qt = 0; qt < 8; ++qt) aacc[r][qt] += e[qt] * inv;
      }
    }
    __syncthreads();
  }

  // ---- elementwise finish: m_c = (abar/8) * z, exact fp32 z from global ----
#pragma unroll
  for (int r = 0; r < 4; ++r) {
    int cc = w * 16 + lk * 4 + r;
    const float* zrow = qz + ((size_t)(b * NC + cc) * NP + p) * ND;
    float* orow = out + ((size_t)(b * NC + cc) * NP + p) * ND;
#pragma unroll
    for (int qt = 0; qt < 8; ++qt) {
      int d = qt * 16 + lm;
      orow[d] = 0.125f * aacc[r][qt] * zrow[d];
    }
  }
}

extern "C" void kernel_launch(void* const* d_in, const int* in_sizes, int n_in,
                              void* d_out, int out_size, void* d_ws, size_t ws_size,
                              hipStream_t stream) {
  const float* qz  = (const float*)d_in[0];
  const float* tuw = (const float*)d_in[1];
  const float* tvw = (const float*)d_in[2];
  const float* cuw = (const float*)d_in[3];
  const float* cvw = (const float*)d_in[4];
  float* out_t = (float*)d_out;
  float* out_c = out_t + (size_t)NB * NC * NP * ND;

  if (ws_size >= W_NEED) {
    short* whi = (short*)d_ws;
    short* wlo = whi + W_ELEMS;
    prep_w<<<256, 256, 0, stream>>>(tuw, tvw, cuw, cvw, whi, wlo);
    tmsg_kernel<1><<<dim3(NC, NB), 512, 0, stream>>>(qz, tuw, tvw, whi, wlo, out_t);
    cmsg_kernel<1><<<dim3(NP, NB), 512, 0, stream>>>(qz, cuw, cvw, whi, wlo, out_c);
  } else {
    tmsg_kernel<0><<<dim3(NC, NB), 512, 0, stream>>>(qz, tuw, tvw, nullptr, nullptr, out_t);
    cmsg_kernel<0><<<dim3(NP, NB), 512, 0, stream>>>(qz, cuw, cvw, nullptr, nullptr, out_c);
  }
}

// Round 8
// 262.784 us; speedup vs baseline: 2.0893x; 2.0893x over previous
//
#include <hip/hip_runtime.h>
#include <math.h>

#define NB 8
#define NC 128
#define NP 96
#define ND 128
#define NH 8
#define NR 16

typedef __attribute__((ext_vector_type(8))) short short8;
typedef __attribute__((ext_vector_type(4))) float f32x4;
typedef __attribute__((ext_vector_type(4))) unsigned u32x4;

#define MFMA(a, b, c) __builtin_amdgcn_mfma_f32_16x16x32_bf16((a), (b), (c), 0, 0, 0)

__device__ __forceinline__ short8 s8(u32x4 u) { return __builtin_bit_cast(short8, u); }

// scalar fp32 -> bf16 (RNE) and back
__device__ __forceinline__ unsigned bfh_u(float x) {
  unsigned u = __float_as_uint(x);
  unsigned r = u + 0x7fffu + ((u >> 16) & 1u);
  return r >> 16;  // bf16 bits in low 16
}
__device__ __forceinline__ short bfh(float x) { return (short)bfh_u(x); }
__device__ __forceinline__ float bff(short s) {
  return __uint_as_float(((unsigned)(unsigned short)s) << 16);
}

// pair split: {hi_packed, lo_packed}, elem a in low 16 bits of each word
__device__ __forceinline__ uint2 split2(float a, float b) {
  unsigned ha = bfh_u(a), hb = bfh_u(b);
  float fa = __uint_as_float(ha << 16), fb = __uint_as_float(hb << 16);
  unsigned la = bfh_u(a - fa), lb = bfh_u(b - fb);
  return make_uint2(ha | (hb << 16), la | (lb << 16));
}

// split 8 consecutive floats into hi/lo packed u32x4
__device__ __forceinline__ void split8(const float4 x0, const float4 x1,
                                       u32x4* hi, u32x4* lo) {
  uint2 r0 = split2(x0.x, x0.y), r1 = split2(x0.z, x0.w);
  uint2 r2 = split2(x1.x, x1.y), r3 = split2(x1.z, x1.w);
  *hi = u32x4{r0.x, r1.x, r2.x, r3.x};
  *lo = u32x4{r0.y, r1.y, r2.y, r3.y};
}

// LDS row strides in shorts
#define TS_Z 136   // z      [rows][136]
#define TS_Q 72    // Q2     [rows][72]
#define TS_T 104   // zT/abar[rows][104]

#define W_ELEMS ((size_t)4 * 8 * 128 * 128)  // 524288 per split
#define W_NEED (W_ELEMS * 2 * 2)             // 2 MB

// ---------------- W split precompute: mats {tu, tv, cu, cv} ----------------
__global__ __launch_bounds__(256)
void prep_w(const float* __restrict__ w0, const float* __restrict__ w1,
            const float* __restrict__ w2, const float* __restrict__ w3,
            short* __restrict__ whi, short* __restrict__ wlo) {
  int t = blockIdx.x * 256 + threadIdx.x;   // 65536 threads, 8 elems each
  int mat = t >> 14;
  size_t off = (size_t)(t & 16383) * 8;
  const float* srcs[4] = {w0, w1, w2, w3};
  const float* s = srcs[mat] + off;
  u32x4 hi, lo;
  split8(*(const float4*)s, *(const float4*)(s + 4), &hi, &lo);
  size_t base = (size_t)mat * 131072 + off;
  *(u32x4*)&whi[base] = hi;
  *(u32x4*)&wlo[base] = lo;
}

// ---------------- time-message kernel: one block per (b,c) ----------------
// R6-proven structure (VGPR 64): per-hp W loads, 2 barriers/hp.
template <int WS>
__global__ __launch_bounds__(512, 4)
void tmsg_kernel(const float* __restrict__ qz, const float* __restrict__ wu,
                 const float* __restrict__ wv, const short* __restrict__ whi,
                 const short* __restrict__ wlo, float* __restrict__ out) {
  __shared__ __align__(16) short smem[39936];
  short* zhi = smem;                   // [96][136]
  short* zlo = smem + NP * TS_Z;
  short* qhi = smem + 2 * NP * TS_Z;   // [96][72]
  short* qlo = qhi + NP * TS_Q;
  short* zthi = smem;                  // [128][104] (phase2, aliased)
  short* ztlo = smem + ND * TS_T;
  short* ahi  = smem + 2 * ND * TS_T;  // [96][104]  (phase2)

  const int tid = threadIdx.x;
  const int l = tid & 63, w = tid >> 6;
  const int lm = l & 15, lk = l >> 4;
  const int c = blockIdx.x, b = blockIdx.y;
  const float* zg = qz + ((size_t)(b * NC + c) * NP) * ND;

  // ---- stage z -> split bf16 ----
  for (int i = tid; i < NP * 32; i += 512) {
    int p = i >> 5, s = i & 31;
    float4 v = ((const float4*)zg)[i];
    uint2 r0 = split2(v.x, v.y), r1 = split2(v.z, v.w);
    *(uint2*)&zhi[p * TS_Z + 4 * s] = make_uint2(r0.x, r1.x);
    *(uint2*)&zlo[p * TS_Z + 4 * s] = make_uint2(r0.y, r1.y);
  }
  __syncthreads();

  const int nt = w & 3, mset = (w >> 2) * 3;  // wave owns fixed nt, 3 m-tiles
  const int vsel = nt & 1, hsel = nt >> 1;
  const float qsc = vsel ? 1.0f : 0.25f;  // fold 1/sqrt(R) into Qu

  float aacc[4][6] = {};
  const short8 z8 = {0, 0, 0, 0, 0, 0, 0, 0};
  const f32x4 zf = {0.f, 0.f, 0.f, 0.f};

  for (int hp = 0; hp < 4; ++hp) {
    const int hd = 2 * hp + hsel;
    // ---- W fragments for this wave's nt (loaded per-hp: keeps VGPR at 64) ----
    u32x4 wbh[4], wbl[4];
    if constexpr (WS) {
      const size_t rb = (((size_t)vsel * 8 + b) * 128 + hd * NR + lm) * 128;
#pragma unroll
      for (int ks = 0; ks < 4; ++ks) {
        wbh[ks] = *(const u32x4*)&whi[rb + ks * 32 + lk * 8];
        wbl[ks] = *(const u32x4*)&wlo[rb + ks * 32 + lk * 8];
      }
    } else {
      const float* wrow = (vsel ? wv : wu) + ((size_t)b * ND + hd * NR + lm) * ND;
#pragma unroll
      for (int ks = 0; ks < 4; ++ks)
        split8(*(const float4*)(wrow + ks * 32 + lk * 8),
               *(const float4*)(wrow + ks * 32 + lk * 8 + 4), &wbh[ks], &wbl[ks]);
    }
    // ---- projection: Q tiles (m, nt) for m in mset..mset+2 ----
    f32x4 pacc[3] = {zf, zf, zf};
#pragma unroll
    for (int ks = 0; ks < 4; ++ks) {
#pragma unroll
      for (int mm = 0; mm < 3; ++mm) {
        int row = (mset + mm) * 16 + lm;
        short8 ah = *(const short8*)&zhi[row * TS_Z + ks * 32 + lk * 8];
        short8 al = *(const short8*)&zlo[row * TS_Z + ks * 32 + lk * 8];
        pacc[mm] = MFMA(ah, s8(wbh[ks]), pacc[mm]);
        pacc[mm] = MFMA(ah, s8(wbl[ks]), pacc[mm]);
        pacc[mm] = MFMA(al, s8(wbh[ks]), pacc[mm]);
      }
    }
#pragma unroll
    for (int mm = 0; mm < 3; ++mm) {
#pragma unroll
      for (int r = 0; r < 4; ++r) {
        float v = pacc[mm][r] * qsc;
        int row = (mset + mm) * 16 + lk * 4 + r, col = nt * 16 + lm;
        short hh = bfh(v);
        qhi[row * TS_Q + col] = hh;
        qlo[row * TS_Q + col] = bfh(v - bff(hh));
      }
    }
    __syncthreads();

    // ---- logits (K=16 zero-padded) + softmax (no max-sub); waves 0-5 ----
    if (w < 6) {
#pragma unroll
      for (int hh = 0; hh < 2; ++hh) {
        short8 ah = z8, al = z8;
        if (l < 32) {
          ah = *(const short8*)&qhi[(w * 16 + lm) * TS_Q + 32 * hh + lk * 8];
          al = *(const short8*)&qlo[(w * 16 + lm) * TS_Q + 32 * hh + lk * 8];
        }
        f32x4 s[6];
#pragma unroll
        for (int qt = 0; qt < 6; ++qt) {
          s[qt] = zf;
          short8 bh = z8, bl = z8;
          if (l < 32) {
            bh = *(const short8*)&qhi[(qt * 16 + lm) * TS_Q + 32 * hh + 16 + lk * 8];
            bl = *(const short8*)&qlo[(qt * 16 + lm) * TS_Q + 32 * hh + 16 + lk * 8];
          }
          s[qt] = MFMA(ah, bh, s[qt]);
          s[qt] = MFMA(ah, bl, s[qt]);
          s[qt] = MFMA(al, bh, s[qt]);
        }
#pragma unroll
        for (int r = 0; r < 4; ++r) {
          float e[6], sum = 0.f;
#pragma unroll
          for (int qt = 0; qt < 6; ++qt) { e[qt] = __expf(s[qt][r]); sum += e[qt]; }
          sum += __shfl_xor(sum, 1);
          sum += __shfl_xor(sum, 2);
          sum += __shfl_xor(sum, 4);
          sum += __shfl_xor(sum, 8);
          float inv = 1.0f / sum;
#pragma unroll
          for (int qt = 0; qt < 6; ++qt) aacc[r][qt] += e[qt] * inv;
        }
      }
    }
    __syncthreads();
  }

  // ---- phase2: build zT split + abar-hi in aliased LDS ----
  for (int i = tid; i < NP * 32; i += 512) {
    int p = i >> 5, s = i & 31;
    float4 v = ((const float4*)zg)[i];
    float f[4] = {v.x, v.y, v.z, v.w};
#pragma unroll
    for (int j = 0; j < 4; ++j) {
      int d = 4 * s + j;
      short hh = bfh(f[j]);
      zthi[d * TS_T + p] = hh;
      ztlo[d * TS_T + p] = bfh(f[j] - bff(hh));
    }
  }
  if (w < 6) {
#pragma unroll
    for (int r = 0; r < 4; ++r)
#pragma unroll
      for (int qt = 0; qt < 6; ++qt)
        ahi[(w * 16 + lk * 4 + r) * TS_T + qt * 16 + lm] = bfh(aacc[r][qt] * 0.125f);
  }
  __syncthreads();

  // ---- PV: m_t = abar @ z ; wave w owns d-tile w; K=96 ----
  float* og = out + ((size_t)(b * NC + c) * NP) * ND;
  f32x4 oacc[6] = {zf, zf, zf, zf, zf, zf};
#pragma unroll
  for (int ks = 0; ks < 3; ++ks) {
    short8 bh = *(const short8*)&zthi[(w * 16 + lm) * TS_T + ks * 32 + lk * 8];
    short8 bl = *(const short8*)&ztlo[(w * 16 + lm) * TS_T + ks * 32 + lk * 8];
#pragma unroll
    for (int m = 0; m < 6; ++m) {
      short8 a = *(const short8*)&ahi[(m * 16 + lm) * TS_T + ks * 32 + lk * 8];
      oacc[m] = MFMA(a, bh, oacc[m]);
      oacc[m] = MFMA(a, bl, oacc[m]);
    }
  }
#pragma unroll
  for (int m = 0; m < 6; ++m)
#pragma unroll
    for (int r = 0; r < 4; ++r)
      og[(m * 16 + lk * 4 + r) * ND + w * 16 + lm] = oacc[m][r];
}

// ---------------- channel-message kernel: one block per (b,p) ----------------
// z A-fragments in REGISTERS; LDS holds only Q (36,864 B).
// launch_bounds(512,4): 128-VGPR cap -> fits ~120-reg footprint, NO spill
// (R7's (512,8) forced a 64-reg cap -> catastrophic scratch traffic).
template <int WS>
__global__ __launch_bounds__(512, 4)
void cmsg_kernel(const float* __restrict__ qz, const float* __restrict__ wu,
                 const float* __restrict__ wv, const short* __restrict__ whi,
                 const short* __restrict__ wlo, float* __restrict__ out) {
  __shared__ __align__(16) short qhi_s[NC * TS_Q];  // [128][72]
  __shared__ __align__(16) short qlo_s[NC * TS_Q];

  const int tid = threadIdx.x;
  const int l = tid & 63, w = tid >> 6;
  const int lm = l & 15, lk = l >> 4;
  const int p = blockIdx.x, b = blockIdx.y;

  // ---- z A-fragments for this wave's m-tile (rows w*16+lm), split in regs ----
  u32x4 zah[4], zal[4];
  {
    const float* zrow = qz + ((size_t)(b * NC + w * 16 + lm) * NP + p) * ND;
#pragma unroll
    for (int ks = 0; ks < 4; ++ks)
      split8(*(const float4*)(zrow + ks * 32 + lk * 8),
             *(const float4*)(zrow + ks * 32 + lk * 8 + 4), &zah[ks], &zal[ks]);
  }

  float aacc[4][8] = {};
  const short8 z8 = {0, 0, 0, 0, 0, 0, 0, 0};
  const f32x4 zf = {0.f, 0.f, 0.f, 0.f};

  for (int hp = 0; hp < 4; ++hp) {
    // ---- projection: wave w computes Q[m-tile w][all 4 nt] ----
#pragma unroll
    for (int nt = 0; nt < 4; ++nt) {
      const int vsel = nt & 1, hd = 2 * hp + (nt >> 1);
      u32x4 wbh[4], wbl[4];
      if constexpr (WS) {
        const size_t rb = (((size_t)(2 + vsel) * 8 + b) * 128 + hd * NR + lm) * 128;
#pragma unroll
        for (int ks = 0; ks < 4; ++ks) {
          wbh[ks] = *(const u32x4*)&whi[rb + ks * 32 + lk * 8];
          wbl[ks] = *(const u32x4*)&wlo[rb + ks * 32 + lk * 8];
        }
      } else {
        const float* wrow = (vsel ? wv : wu) + ((size_t)b * ND + hd * NR + lm) * ND;
#pragma unroll
        for (int ks = 0; ks < 4; ++ks)
          split8(*(const float4*)(wrow + ks * 32 + lk * 8),
                 *(const float4*)(wrow + ks * 32 + lk * 8 + 4), &wbh[ks], &wbl[ks]);
      }
      f32x4 pacc = zf;
#pragma unroll
      for (int ks = 0; ks < 4; ++ks) {
        pacc = MFMA(s8(zah[ks]), s8(wbh[ks]), pacc);
        pacc = MFMA(s8(zah[ks]), s8(wbl[ks]), pacc);
        pacc = MFMA(s8(zal[ks]), s8(wbh[ks]), pacc);
      }
      const float qsc = vsel ? 1.0f : 0.25f;
#pragma unroll
      for (int r = 0; r < 4; ++r) {
        float v = pacc[r] * qsc;
        int row = w * 16 + lk * 4 + r, col = nt * 16 + lm;
        short hh = bfh(v);
        qhi_s[row * TS_Q + col] = hh;
        qlo_s[row * TS_Q + col] = bfh(v - bff(hh));
      }
    }
    __syncthreads();

    // ---- logits (K=16 padded) + softmax over d' (no max-sub) ----
#pragma unroll
    for (int hh = 0; hh < 2; ++hh) {
      short8 ah = z8, al = z8;
      if (l < 32) {
        ah = *(const short8*)&qhi_s[(w * 16 + lm) * TS_Q + 32 * hh + lk * 8];
        al = *(const short8*)&qlo_s[(w * 16 + lm) * TS_Q + 32 * hh + lk * 8];
      }
      f32x4 s[8];
#pragma unroll
      for (int qt = 0; qt < 8; ++qt) {
        s[qt] = zf;
        short8 bh = z8, bl = z8;
        if (l < 32) {
          bh = *(const short8*)&qhi_s[(qt * 16 + lm) * TS_Q + 32 * hh + 16 + lk * 8];
          bl = *(const short8*)&qlo_s[(qt * 16 + lm) * TS_Q + 32 * hh + 16 + lk * 8];
        }
        s[qt] = MFMA(ah, bh, s[qt]);
        s[qt] = MFMA(ah, bl, s[qt]);
        s[qt] = MFMA(al, bh, s[qt]);
      }
#pragma unroll
      for (int r = 0; r < 4; ++r) {
        float e[8], sum = 0.f;
#pragma unroll
        for (int qt = 0; qt < 8; ++qt) { e[qt] = __expf(s[qt][r]); sum += e[qt]; }
        sum += __shfl_xor(sum, 1);
        sum += __shfl_xor(sum, 2);
        sum += __shfl_xor(sum, 4);
        sum += __shfl_xor(sum, 8);
        float inv = 1.0f / sum;
#pragma unroll
        for (int qt = 0; qt < 8; ++qt) aacc[r][qt] += e[qt] * inv;
      }
    }
    __syncthreads();
  }

  // ---- elementwise finish: m_c = (abar/8) * z, exact fp32 z from global ----
#pragma unroll
  for (int r = 0; r < 4; ++r) {
    int cc = w * 16 + lk * 4 + r;
    const float* zrow = qz + ((size_t)(b * NC + cc) * NP + p) * ND;
    float* orow = out + ((size_t)(b * NC + cc) * NP + p) * ND;
#pragma unroll
    for (int qt = 0; qt < 8; ++qt) {
      int d = qt * 16 + lm;
      orow[d] = 0.125f * aacc[r][qt] * zrow[d];
    }
  }
}

extern "C" void kernel_launch(void* const* d_in, const int* in_sizes, int n_in,
                              void* d_out, int out_size, void* d_ws, size_t ws_size,
                              hipStream_t stream) {
  const float* qz  = (const float*)d_in[0];
  const float* tuw = (const float*)d_in[1];
  const float* tvw = (const float*)d_in[2];
  const float* cuw = (const float*)d_in[3];
  const float* cvw = (const float*)d_in[4];
  float* out_t = (float*)d_out;
  float* out_c = out_t + (size_t)NB * NC * NP * ND;

  if (ws_size >= W_NEED) {
    short* whi = (short*)d_ws;
    short* wlo = whi + W_ELEMS;
    prep_w<<<256, 256, 0, stream>>>(tuw, tvw, cuw, cvw, whi, wlo);
    tmsg_kernel<1><<<dim3(NC, NB), 512, 0, stream>>>(qz, tuw, tvw, whi, wlo, out_t);
    cmsg_kernel<1><<<dim3(NP, NB), 512, 0, stream>>>(qz, cuw, cvw, whi, wlo, out_c);
  } else {
    tmsg_kernel<0><<<dim3(NC, NB), 512, 0, stream>>>(qz, tuw, tvw, nullptr, nullptr, out_t);
    cmsg_kernel<0><<<dim3(NP, NB), 512, 0, stream>>>(qz, cuw, cvw, nullptr, nullptr, out_c);
  }
}